// Round 5
// baseline (831.883 us; speedup 1.0000x reference)
//
#include <hip/hip_runtime.h>
#include <hip/hip_bf16.h>
#include <hip/hip_cooperative_groups.h>
#include <cstddef>
#include <cstdint>

namespace cg = cooperative_groups;

#define NN 4096
#define KP 512          // padded K (501 real cols)
#define KTOT 501

typedef __attribute__((ext_vector_type(8))) short short8;
typedef __attribute__((ext_vector_type(4))) float f32x4;

#define GLB(p) ((const __attribute__((address_space(1))) void*)(p))
#define LDS(p) ((__attribute__((address_space(3))) void*)(p))

// phi(x) = sin(pi x)/(pi x) * exp(-x^2/(2*3.2^2)), phi(0)=1.
__device__ __forceinline__ float phi_eval(float x) {
    if (x == 0.0f) return 1.0f;
    const float PI_F = 3.14159265358979323846f;
    float rn = rintf(x);
    float r  = x - rn;
    float s  = __sinf(PI_F * r);
    if (((int)rn) & 1) s = -s;
    float e  = __expf(-x * x * (1.0f / 20.48f));
    return __fdividef(s * e, PI_F * x);
}

__device__ __forceinline__ void col_to_level(int col, int& l, int& off) {
    if      (col < 17)  { l = 0; off = 0;   }
    else if (col < 50)  { l = 1; off = 17;  }
    else if (col < 115) { l = 2; off = 50;  }
    else                { l = (col < 244) ? 3 : 4; off = (col < 244) ? 115 : 244; }
}

__device__ __forceinline__ void split_bf16(float v, unsigned short& h, unsigned short& l) {
    __hip_bfloat16 hb = __float2bfloat16(v);
    __hip_bfloat16 lb = __float2bfloat16(v - __bfloat162float(hb));
    h = *(unsigned short*)&hb;
    l = *(unsigned short*)&lb;
}

// ---- cooperative chain phases -------------------------------------------

template<int T, int OFF>
__device__ void phase_build_C(const float* __restrict__ img, const int* __restrict__ idxAll,
                              const float* __restrict__ Usm, const float* __restrict__ PhiR,
                              float* __restrict__ CdT, int gid, int gthreads) {
    for (int i = gid; i < T * T; i += gthreads) {
        int p = i / T, q = i - p * T;
        int ip = idxAll[OFF + p];
        int iq = idxAll[KTOT + OFF + q];
        float f = img[(size_t)ip * NN + iq];
        float val;
        if (OFF == 0) {
            val = f;
        } else {
            const float* Ur = Usm  + (size_t)(OFF + p) * KP;   // 16B aligned
            const float* Pr = PhiR + (size_t)iq * KP;          // 16B aligned
            float s0 = 0.f, s1 = 0.f, s2 = 0.f, s3 = 0.f;
            int k = 0;
            #pragma unroll 4
            for (; k + 4 <= OFF; k += 4) {
                float4 a = *(const float4*)(Ur + k);
                float4 b = *(const float4*)(Pr + k);
                s0 += a.x * b.x; s1 += a.y * b.y; s2 += a.z * b.z; s3 += a.w * b.w;
            }
            float u = (s0 + s1) + (s2 + s3);
            for (; k < OFF; ++k) u += Ur[k] * Pr[k];
            float d = f - u;
            val = (fabsf(d) > 0.01f) ? d : 0.0f;
        }
        CdT[(size_t)(OFF + q) * KP + (OFF + p)] = val;   // dense transposed
    }
}

template<int T, int OFF>
__device__ void phase_update(const float* __restrict__ PhiC, const int* __restrict__ idxAll,
                             const float* __restrict__ CdT, float* __restrict__ Usm,
                             int gid, int gthreads) {
    constexpr int HEAD = (4 - (OFF & 3)) & 3;
    for (int i = gid; i < KTOT * T; i += gthreads) {
        int r = i / T, t = i - r * T;
        const float* a = PhiC + (size_t)idxAll[r] * KP + OFF;
        const float* b = CdT  + (size_t)(OFF + t) * KP + OFF;
        float s = 0.f;
        int k = 0;
        #pragma unroll
        for (; k < HEAD; ++k) s += a[k] * b[k];
        float s0 = 0.f, s1 = 0.f, s2 = 0.f, s3 = 0.f;
        #pragma unroll 4
        for (; k + 4 <= T; k += 4) {
            float4 x = *(const float4*)(a + k);
            float4 y = *(const float4*)(b + k);
            s0 += x.x * y.x; s1 += x.y * y.y; s2 += x.z * y.z; s3 += x.w * y.w;
        }
        s += (s0 + s1) + (s2 + s3);
        for (; k < T; ++k) s += a[k] * b[k];
        Usm[(size_t)r * KP + OFF + t] = s;
    }
}

__device__ void phase_split(const float* __restrict__ src, unsigned short* __restrict__ hi,
                            unsigned short* __restrict__ lo, int ngroups, int gid, int gthreads) {
    for (int g = gid; g < ngroups; g += gthreads) {
        int i = g * 4;
        float4 v = *(const float4*)(src + i);
        unsigned short h[4], l[4];
        split_bf16(v.x, h[0], l[0]);
        split_bf16(v.y, h[1], l[1]);
        split_bf16(v.z, h[2], l[2]);
        split_bf16(v.w, h[3], l[3]);
        *(ushort4*)(hi + i) = *(const ushort4*)h;
        *(ushort4*)(lo + i) = *(const ushort4*)l;
    }
}

// One cooperative kernel: phi+nearest+zero -> 5-level chain -> splits.
__global__ __launch_bounds__(256, 2)
void chain_kernel(const float* __restrict__ img, const float* __restrict__ xc,
                  const float* __restrict__ xr,
                  float* __restrict__ PhiC, float* __restrict__ PhiR,
                  float* __restrict__ CdT, float* __restrict__ Usm, int* __restrict__ idxAll,
                  unsigned short* PRh, unsigned short* PRl,
                  unsigned short* PCh, unsigned short* PCl,
                  unsigned short* Ch,  unsigned short* Cl) {
    cg::grid_group grid = cg::this_grid();
    const int tid = threadIdx.x;
    const int bid = blockIdx.x;
    const int gthreads = gridDim.x * 256;
    const int gid = bid * 256 + tid;

    // P0a: Phi tables (incl. zero pad cols)
    for (int i = gid; i < NN * KP; i += gthreads) {
        int n = i >> 9, col = i & 511;
        float pc = 0.f, pr = 0.f;
        if (col < KTOT) {
            int l, off; col_to_level(col, l, off);
            int s = 8 << l;
            float fo = (float)(col - off - s);
            float fs = (float)s;
            pc = phi_eval(fs * xc[n] - fo);
            pr = phi_eval(fs * xr[n] - fo);
        }
        PhiC[i] = pc;
        PhiR[i] = pr;
    }
    // P0b: zero dense CdT
    for (int i = gid; i < KP * KP; i += gthreads) CdT[i] = 0.f;
    // P0c: nearest indices (one block per target, grid-stride over 1002 targets)
    __shared__ float sv[256];
    __shared__ int   si[256];
    for (int task = bid; task < 2 * KTOT; task += gridDim.x) {
        int side = (task >= KTOT);
        int col  = side ? task - KTOT : task;
        const float* x = side ? xr : xc;
        int l, off; col_to_level(col, l, off);
        int s = 8 << l;
        float target = (float)(col - off - s) / (float)s;
        float best = 1e30f; int bidx = 0;
        for (int n = tid; n < NN; n += 256) {
            float d = fabsf(x[n] - target);
            if (d < best) { best = d; bidx = n; }
        }
        sv[tid] = best; si[tid] = bidx;
        __syncthreads();
        for (int w = 128; w > 0; w >>= 1) {
            if (tid < w) {
                float ov = sv[tid + w]; int oi = si[tid + w];
                if (ov < sv[tid] || (ov == sv[tid] && oi < si[tid])) { sv[tid] = ov; si[tid] = oi; }
            }
            __syncthreads();
        }
        if (tid == 0) idxAll[task] = si[0];
        __syncthreads();
    }
    grid.sync();

    // level chain (build -> sync -> update -> sync)
    phase_build_C<17, 0>(img, idxAll, Usm, PhiR, CdT, gid, gthreads);
    grid.sync();
    phase_update<17, 0>(PhiC, idxAll, CdT, Usm, gid, gthreads);
    grid.sync();
    phase_build_C<33, 17>(img, idxAll, Usm, PhiR, CdT, gid, gthreads);
    grid.sync();
    phase_update<33, 17>(PhiC, idxAll, CdT, Usm, gid, gthreads);
    grid.sync();
    phase_build_C<65, 50>(img, idxAll, Usm, PhiR, CdT, gid, gthreads);
    grid.sync();
    phase_update<65, 50>(PhiC, idxAll, CdT, Usm, gid, gthreads);
    grid.sync();
    phase_build_C<129, 115>(img, idxAll, Usm, PhiR, CdT, gid, gthreads);
    grid.sync();
    phase_update<129, 115>(PhiC, idxAll, CdT, Usm, gid, gthreads);
    grid.sync();
    phase_build_C<257, 244>(img, idxAll, Usm, PhiR, CdT, gid, gthreads);
    grid.sync();

    // splits. PhiR+CdT first (PRh/PRl overlay Usm region — dead now).
    phase_split(PhiR, PRh, PRl, NN * KP / 4, gid, gthreads);
    phase_split(CdT,  Ch,  Cl,  KP * KP / 4, gid, gthreads);
    grid.sync();
    // PhiC split overwrites the PhiR fp32 region — must come after PhiR is split.
    phase_split(PhiC, PCh, PCl, NN * KP / 4, gid, gthreads);
}

// ---- MFMA GEMMs (unchanged, known-good) ---------------------------------

#define GEMM_BODY(Ahi_, Alo_, Bhi_, Blo_)                                              \
    __shared__ short As_h[128][32];                                                    \
    __shared__ short As_l[128][32];                                                    \
    __shared__ short Bs_h[128][32];                                                    \
    __shared__ short Bs_l[128][32];                                                    \
    const int tid  = threadIdx.x;                                                      \
    const int lane = tid & 63;                                                         \
    const int wave = tid >> 6;                                                         \
    const int wr   = wave >> 1;                                                        \
    const int wc   = wave & 1;                                                         \
    const int row0 = blockIdx.y * 128;                                                 \
    const int col0 = blockIdx.x * 128;                                                 \
    f32x4 acc[4][4];                                                                   \
    _Pragma("unroll")                                                                  \
    for (int i = 0; i < 4; ++i)                                                        \
        _Pragma("unroll")                                                              \
        for (int j = 0; j < 4; ++j) acc[i][j] = (f32x4){0.f, 0.f, 0.f, 0.f};           \
    const int srow = lane >> 2;                                                        \
    const int scol = (lane & 3) * 8;                                                   \
    for (int kc = 0; kc < 16; ++kc) {                                                  \
        const int k0 = kc * 32;                                                        \
        _Pragma("unroll")                                                              \
        for (int s = 0; s < 2; ++s) {                                                  \
            const int rseg = wave * 32 + s * 16;                                       \
            const int r    = rseg + srow;                                              \
            const size_t ga = (size_t)(row0 + r) * KP + k0 + scol;                     \
            const size_t gb = (size_t)(col0 + r) * KP + k0 + scol;                     \
            __builtin_amdgcn_global_load_lds(GLB(Ahi_ + ga), LDS(&As_h[rseg][0]), 16, 0, 0); \
            __builtin_amdgcn_global_load_lds(GLB(Alo_ + ga), LDS(&As_l[rseg][0]), 16, 0, 0); \
            __builtin_amdgcn_global_load_lds(GLB(Bhi_ + gb), LDS(&Bs_h[rseg][0]), 16, 0, 0); \
            __builtin_amdgcn_global_load_lds(GLB(Blo_ + gb), LDS(&Bs_l[rseg][0]), 16, 0, 0); \
        }                                                                              \
        __syncthreads();                                                               \
        const int kb = (lane >> 4) * 8;                                                \
        short8 ah[4], al[4], bh[4], bl[4];                                             \
        _Pragma("unroll")                                                              \
        for (int mb = 0; mb < 4; ++mb) {                                               \
            const int rr = wr * 64 + mb * 16 + (lane & 15);                            \
            ah[mb] = *(const short8*)&As_h[rr][kb];                                    \
            al[mb] = *(const short8*)&As_l[rr][kb];                                    \
        }                                                                              \
        _Pragma("unroll")                                                              \
        for (int nb = 0; nb < 4; ++nb) {                                               \
            const int cc = wc * 64 + nb * 16 + (lane & 15);                            \
            bh[nb] = *(const short8*)&Bs_h[cc][kb];                                    \
            bl[nb] = *(const short8*)&Bs_l[cc][kb];                                    \
        }                                                                              \
        _Pragma("unroll")                                                              \
        for (int mb = 0; mb < 4; ++mb)                                                 \
            _Pragma("unroll")                                                          \
            for (int nb = 0; nb < 4; ++nb) {                                           \
                acc[mb][nb] = __builtin_amdgcn_mfma_f32_16x16x32_bf16(ah[mb], bh[nb], acc[mb][nb], 0, 0, 0); \
                acc[mb][nb] = __builtin_amdgcn_mfma_f32_16x16x32_bf16(ah[mb], bl[nb], acc[mb][nb], 0, 0, 0); \
                acc[mb][nb] = __builtin_amdgcn_mfma_f32_16x16x32_bf16(al[mb], bh[nb], acc[mb][nb], 0, 0, 0); \
            }                                                                          \
        __syncthreads();                                                               \
    }                                                                                  \
    const int orow = (lane >> 4) * 4;                                                  \
    const int ocol = lane & 15;

__global__ __launch_bounds__(256) void gemm_mfma_f32out(const short* __restrict__ Ahi,
                                                        const short* __restrict__ Alo,
                                                        const short* __restrict__ Bhi,
                                                        const short* __restrict__ Blo,
                                                        float* __restrict__ out) {
    GEMM_BODY(Ahi, Alo, Bhi, Blo)
    #pragma unroll
    for (int mb = 0; mb < 4; ++mb)
        #pragma unroll
        for (int nb = 0; nb < 4; ++nb) {
            const int col = col0 + wc * 64 + nb * 16 + ocol;
            #pragma unroll
            for (int reg = 0; reg < 4; ++reg) {
                const int row = row0 + wr * 64 + mb * 16 + orow + reg;
                out[(size_t)row * NN + col] = acc[mb][nb][reg];
            }
        }
}

__global__ __launch_bounds__(256) void gemm_mfma_splitout(const short* __restrict__ Ahi,
                                                          const short* __restrict__ Alo,
                                                          const short* __restrict__ Bhi,
                                                          const short* __restrict__ Blo,
                                                          unsigned short* __restrict__ Oh,
                                                          unsigned short* __restrict__ Ol) {
    GEMM_BODY(Ahi, Alo, Bhi, Blo)
    #pragma unroll
    for (int mb = 0; mb < 4; ++mb)
        #pragma unroll
        for (int nb = 0; nb < 4; ++nb) {
            const int col = col0 + wc * 64 + nb * 16 + ocol;
            #pragma unroll
            for (int reg = 0; reg < 4; ++reg) {
                const int row = row0 + wr * 64 + mb * 16 + orow + reg;
                unsigned short h, l;
                split_bf16(acc[mb][nb][reg], h, l);
                Oh[(size_t)row * KP + col] = h;
                Ol[(size_t)row * KP + col] = l;
            }
        }
}

extern "C" void kernel_launch(void* const* d_in, const int* in_sizes, int n_in,
                              void* d_out, int out_size, void* d_ws, size_t ws_size,
                              hipStream_t stream) {
    const float* img = (const float*)d_in[0];
    const float* xc  = (const float*)d_in[1];
    const float* xr  = (const float*)d_in[2];
    float* out = (float*)d_out;

    const size_t M2 = (size_t)NN * KP;
    // ws layout (floats): PhiC(2M) | PhiR(2M) | Ubuf(2M) | CdT(256K) | CdTsplit(256K) | idx
    float* PhiC = (float*)d_ws;
    float* PhiR = PhiC + M2;
    float* Ubuf = PhiR + M2;
    float* CdT  = Ubuf + M2;
    float* CdTs = CdT + (size_t)KP * KP;
    int*   idxAll = (int*)(CdTs + (size_t)KP * KP);
    float* Usm  = Ubuf;                             // 501x512 during chain
    unsigned short* PRh = (unsigned short*)Ubuf;    // split(PhiR) -> Ubuf region
    unsigned short* PRl = PRh + M2;
    unsigned short* PCh = (unsigned short*)PhiR;    // split(PhiC) -> PhiR region
    unsigned short* PCl = PCh + M2;
    unsigned short* Ch  = (unsigned short*)CdTs;
    unsigned short* Cl  = Ch + (size_t)KP * KP;
    unsigned short* Uh  = (unsigned short*)PhiC;    // gemm1 out -> PhiC region
    unsigned short* Ul  = Uh + M2;

    void* args[] = { (void*)&img, (void*)&xc, (void*)&xr,
                     (void*)&PhiC, (void*)&PhiR, (void*)&CdT, (void*)&Usm, (void*)&idxAll,
                     (void*)&PRh, (void*)&PRl, (void*)&PCh, (void*)&PCl,
                     (void*)&Ch, (void*)&Cl };
    hipLaunchCooperativeKernel(reinterpret_cast<void*>(chain_kernel),
                               dim3(512), dim3(256), args, 0, stream);

    // gemm1: U(4096x512) = PhiC x CdT^T, split-bf16 out (overwrites PhiC region)
    gemm_mfma_splitout<<<dim3(KP / 128, NN / 128), 256, 0, stream>>>(
        (const short*)PCh, (const short*)PCl, (const short*)Ch, (const short*)Cl, Uh, Ul);

    // gemm2: out(4096x4096) = U x PhiR^T
    gemm_mfma_f32out<<<dim3(NN / 128, NN / 128), 256, 0, stream>>>(
        (const short*)Uh, (const short*)Ul, (const short*)PRh, (const short*)PRl, out);
}

// Round 6
// 365.470 us; speedup vs baseline: 2.2762x; 2.2762x over previous
//
#include <hip/hip_runtime.h>
#include <hip/hip_bf16.h>
#include <cstddef>
#include <cstdint>

#define NN 4096
#define KP 512          // padded K (501 real cols)
#define KTOT 501

typedef __attribute__((ext_vector_type(8))) short short8;
typedef __attribute__((ext_vector_type(4))) float f32x4;

#define GLB(p) ((const __attribute__((address_space(1))) void*)(p))
#define LDS(p) ((__attribute__((address_space(3))) void*)(p))

// phi(x) = sin(pi x)/(pi x) * exp(-x^2/(2*3.2^2)), phi(0)=1.
__device__ __forceinline__ float phi_eval(float x) {
    if (x == 0.0f) return 1.0f;
    const float PI_F = 3.14159265358979323846f;
    float rn = rintf(x);
    float r  = x - rn;
    float s  = __sinf(PI_F * r);
    if (((int)rn) & 1) s = -s;
    float e  = __expf(-x * x * (1.0f / 20.48f));
    return __fdividef(s * e, PI_F * x);
}

__device__ __forceinline__ void col_to_level(int col, int& l, int& off) {
    if      (col < 17)  { l = 0; off = 0;   }
    else if (col < 50)  { l = 1; off = 17;  }
    else if (col < 115) { l = 2; off = 50;  }
    else                { l = (col < 244) ? 3 : 4; off = (col < 244) ? 115 : 244; }
}

__device__ __forceinline__ void split_bf16(float v, unsigned short& h, unsigned short& l) {
    __hip_bfloat16 hb = __float2bfloat16(v);
    __hip_bfloat16 lb = __float2bfloat16(v - __bfloat162float(hb));
    h = *(unsigned short*)&hb;
    l = *(unsigned short*)&lb;
}

// ---- chain phase templates ----------------------------------------------

template<int T, int OFF>
__device__ void phase_build_C(const float* __restrict__ img, const int* __restrict__ idxAll,
                              const float* __restrict__ Usm, const float* __restrict__ PhiR,
                              float* __restrict__ CdT, int gid, int gthreads) {
    for (int i = gid; i < T * T; i += gthreads) {
        int p = i / T, q = i - p * T;
        int ip = idxAll[OFF + p];
        int iq = idxAll[KTOT + OFF + q];
        float f = img[(size_t)ip * NN + iq];
        float val;
        if (OFF == 0) {
            val = f;
        } else {
            const float* Ur = Usm  + (size_t)(OFF + p) * KP;   // 16B aligned
            const float* Pr = PhiR + (size_t)iq * KP;          // 16B aligned
            float s0 = 0.f, s1 = 0.f, s2 = 0.f, s3 = 0.f;
            int k = 0;
            #pragma unroll 4
            for (; k + 4 <= OFF; k += 4) {
                float4 a = *(const float4*)(Ur + k);
                float4 b = *(const float4*)(Pr + k);
                s0 += a.x * b.x; s1 += a.y * b.y; s2 += a.z * b.z; s3 += a.w * b.w;
            }
            float u = (s0 + s1) + (s2 + s3);
            for (; k < OFF; ++k) u += Ur[k] * Pr[k];
            float d = f - u;
            val = (fabsf(d) > 0.01f) ? d : 0.0f;
        }
        CdT[(size_t)(OFF + q) * KP + (OFF + p)] = val;   // dense transposed
    }
}

template<int T, int OFF>
__device__ void phase_update(const float* __restrict__ PhiC, const int* __restrict__ idxAll,
                             const float* __restrict__ CdT, float* __restrict__ Usm,
                             int gid, int gthreads) {
    constexpr int HEAD = (4 - (OFF & 3)) & 3;
    for (int i = gid; i < KTOT * T; i += gthreads) {
        int r = i / T, t = i - r * T;
        const float* a = PhiC + (size_t)idxAll[r] * KP + OFF;
        const float* b = CdT  + (size_t)(OFF + t) * KP + OFF;
        float s = 0.f;
        int k = 0;
        #pragma unroll
        for (; k < HEAD; ++k) s += a[k] * b[k];
        float s0 = 0.f, s1 = 0.f, s2 = 0.f, s3 = 0.f;
        #pragma unroll 4
        for (; k + 4 <= T; k += 4) {
            float4 x = *(const float4*)(a + k);
            float4 y = *(const float4*)(b + k);
            s0 += x.x * y.x; s1 += x.y * y.y; s2 += x.z * y.z; s3 += x.w * y.w;
        }
        s += (s0 + s1) + (s2 + s3);
        for (; k < T; ++k) s += a[k] * b[k];
        Usm[(size_t)r * KP + OFF + t] = s;
    }
}

// ---- kernel 1: fused prep (phi tables + nearest + zero CdT) -------------
// grid 2058 x 256: blocks [0,1002) nearest, [1002,2026) phi, [2026,2058) zero.
__global__ __launch_bounds__(256) void fused_pre(const float* __restrict__ xc,
                                                 const float* __restrict__ xr,
                                                 float* __restrict__ PhiC, float* __restrict__ PhiR,
                                                 float* __restrict__ CdT, int* __restrict__ idxAll) {
    __shared__ float sv[256];
    __shared__ int   si[256];
    const int b = blockIdx.x;
    const int tid = threadIdx.x;
    if (b < 2 * KTOT) {
        int side = (b >= KTOT);
        int col  = side ? b - KTOT : b;
        const float* x = side ? xr : xc;
        int l, off; col_to_level(col, l, off);
        int s = 8 << l;
        float target = (float)(col - off - s) / (float)s;
        float best = 1e30f; int bidx = 0;
        for (int n = tid; n < NN; n += 256) {
            float d = fabsf(x[n] - target);
            if (d < best) { best = d; bidx = n; }
        }
        sv[tid] = best; si[tid] = bidx;
        __syncthreads();
        for (int w = 128; w > 0; w >>= 1) {
            if (tid < w) {
                float ov = sv[tid + w]; int oi = si[tid + w];
                if (ov < sv[tid] || (ov == sv[tid] && oi < si[tid])) { sv[tid] = ov; si[tid] = oi; }
            }
            __syncthreads();
        }
        if (tid == 0) idxAll[b] = si[0];
    } else if (b < 2026) {
        const int i0 = (b - 1002) * 2048 + tid;
        #pragma unroll
        for (int j = 0; j < 8; ++j) {
            int i = i0 + j * 256;
            int n = i >> 9, col = i & 511;
            float pc = 0.f, pr = 0.f;
            if (col < KTOT) {
                int l, off; col_to_level(col, l, off);
                int s = 8 << l;
                float fo = (float)(col - off - s);
                float fs = (float)s;
                pc = phi_eval(fs * xc[n] - fo);
                pr = phi_eval(fs * xr[n] - fo);
            }
            PhiC[i] = pc;
            PhiR[i] = pr;
        }
    } else {
        const int g0 = (b - 2026) * 256 + tid;        // 8192 threads, 65536 float4 groups
        #pragma unroll
        for (int j = 0; j < 8; ++j) {
            int g = g0 + j * 8192;
            *(float4*)(CdT + (size_t)g * 4) = make_float4(0.f, 0.f, 0.f, 0.f);
        }
    }
}

// ---- kernel 2: levels 0-2 chain in ONE workgroup (syncthreads barriers) --
__global__ __launch_bounds__(1024) void chain012(const float* __restrict__ img,
                                                 const int* __restrict__ idxAll,
                                                 const float* __restrict__ PhiC,
                                                 const float* __restrict__ PhiR,
                                                 float* __restrict__ CdT,
                                                 float* __restrict__ Usm) {
    const int gid = threadIdx.x;
    const int gthreads = 1024;
    phase_build_C<17, 0>(img, idxAll, Usm, PhiR, CdT, gid, gthreads);
    __syncthreads();
    phase_update<17, 0>(PhiC, idxAll, CdT, Usm, gid, gthreads);
    __syncthreads();
    phase_build_C<33, 17>(img, idxAll, Usm, PhiR, CdT, gid, gthreads);
    __syncthreads();
    phase_update<33, 17>(PhiC, idxAll, CdT, Usm, gid, gthreads);
    __syncthreads();
    phase_build_C<65, 50>(img, idxAll, Usm, PhiR, CdT, gid, gthreads);
}

// ---- heavy chain phases as standalone launches --------------------------
template<int T, int OFF>
__global__ __launch_bounds__(256) void update_wrap(const float* __restrict__ PhiC,
                                                   const int* __restrict__ idxAll,
                                                   const float* __restrict__ CdT,
                                                   float* __restrict__ Usm) {
    phase_update<T, OFF>(PhiC, idxAll, CdT, Usm, blockIdx.x * 256 + threadIdx.x, gridDim.x * 256);
}

template<int T, int OFF>
__global__ __launch_bounds__(256) void build_wrap(const float* __restrict__ img,
                                                  const int* __restrict__ idxAll,
                                                  const float* __restrict__ Usm,
                                                  const float* __restrict__ PhiR,
                                                  float* __restrict__ CdT) {
    phase_build_C<T, OFF>(img, idxAll, Usm, PhiR, CdT, blockIdx.x * 256 + threadIdx.x, gridDim.x * 256);
}

// ---- splits -------------------------------------------------------------
__device__ __forceinline__ void split4(const float* __restrict__ src,
                                       unsigned short* __restrict__ hi,
                                       unsigned short* __restrict__ lo, int i) {
    float4 v = *(const float4*)(src + i);
    unsigned short h[4], l[4];
    split_bf16(v.x, h[0], l[0]);
    split_bf16(v.y, h[1], l[1]);
    split_bf16(v.z, h[2], l[2]);
    split_bf16(v.w, h[3], l[3]);
    *(ushort4*)(hi + i) = *(const ushort4*)h;
    *(ushort4*)(lo + i) = *(const ushort4*)l;
}

// splits PhiR (2M) and CdT (256K) in one launch. grid 1152x256, 2 groups/thread.
__global__ __launch_bounds__(256) void split_two(const float* __restrict__ PhiR,
                                                 unsigned short* __restrict__ PRh,
                                                 unsigned short* __restrict__ PRl,
                                                 const float* __restrict__ CdT,
                                                 unsigned short* __restrict__ Ch,
                                                 unsigned short* __restrict__ Cl) {
    const int g0 = blockIdx.x * 256 + threadIdx.x;
    const int NG1 = NN * KP / 4;        // 524288
    const int NGT = NG1 + KP * KP / 4;  // 589824
    for (int g = g0; g < NGT; g += 294912) {
        if (g < NG1) split4(PhiR, PRh, PRl, g * 4);
        else         split4(CdT, Ch, Cl, (g - NG1) * 4);
    }
}

__global__ __launch_bounds__(256) void split_one(const float* __restrict__ src,
                                                 unsigned short* __restrict__ hi,
                                                 unsigned short* __restrict__ lo) {
    const int g0 = blockIdx.x * 256 + threadIdx.x;
    #pragma unroll
    for (int j = 0; j < 2; ++j) split4(src, hi, lo, (g0 + j * 262144) * 4);
}

// ---- MFMA GEMMs with per-tile k-chunk skipping --------------------------
// Chunk list from sorted x: per level, support |s*x - k| <= 12.5 (|phi|<3e-5
// outside). XBASE_ = tile base row/col into XARR_; 128 consecutive sorted x.
#define GEMM_BODY(Ahi_, Alo_, Bhi_, Blo_, XARR_, XBASE_)                               \
    __shared__ short As_h[128][32];                                                    \
    __shared__ short As_l[128][32];                                                    \
    __shared__ short Bs_h[128][32];                                                    \
    __shared__ short Bs_l[128][32];                                                    \
    const int tid  = threadIdx.x;                                                      \
    const int lane = tid & 63;                                                         \
    const int wave = tid >> 6;                                                         \
    const int wr   = wave >> 1;                                                        \
    const int wc   = wave & 1;                                                         \
    const int row0 = blockIdx.y * 128;                                                 \
    const int col0 = blockIdx.x * 128;                                                 \
    int list[16]; int nch = 0;                                                         \
    {                                                                                  \
        float xmn = XARR_[XBASE_];                                                     \
        float xmx = XARR_[(XBASE_) + 127];                                             \
        int mask = 0;                                                                  \
        const int off_[5] = {0, 17, 50, 115, 244};                                     \
        _Pragma("unroll")                                                              \
        for (int l = 0; l < 5; ++l) {                                                  \
            int s_ = 8 << l;                                                           \
            int clo = off_[l] + s_ + (int)floorf(s_ * xmn - 12.5f);                    \
            int chi = off_[l] + s_ + (int)ceilf (s_ * xmx + 12.5f);                    \
            if (clo < off_[l]) clo = off_[l];                                          \
            if (chi > off_[l] + 2 * s_) chi = off_[l] + 2 * s_;                        \
            for (int c = clo >> 5; c <= (chi >> 5); ++c) mask |= 1 << c;               \
        }                                                                              \
        for (int c = 0; c < 16; ++c) if ((mask >> c) & 1) list[nch++] = c;             \
    }                                                                                  \
    f32x4 acc[4][4];                                                                   \
    _Pragma("unroll")                                                                  \
    for (int i = 0; i < 4; ++i)                                                        \
        _Pragma("unroll")                                                              \
        for (int j = 0; j < 4; ++j) acc[i][j] = (f32x4){0.f, 0.f, 0.f, 0.f};           \
    const int srow = lane >> 2;                                                        \
    const int scol = (lane & 3) * 8;                                                   \
    for (int ic = 0; ic < nch; ++ic) {                                                 \
        const int k0 = list[ic] * 32;                                                  \
        _Pragma("unroll")                                                              \
        for (int s = 0; s < 2; ++s) {                                                  \
            const int rseg = wave * 32 + s * 16;                                       \
            const int r    = rseg + srow;                                              \
            const size_t ga = (size_t)(row0 + r) * KP + k0 + scol;                     \
            const size_t gb = (size_t)(col0 + r) * KP + k0 + scol;                     \
            __builtin_amdgcn_global_load_lds(GLB(Ahi_ + ga), LDS(&As_h[rseg][0]), 16, 0, 0); \
            __builtin_amdgcn_global_load_lds(GLB(Alo_ + ga), LDS(&As_l[rseg][0]), 16, 0, 0); \
            __builtin_amdgcn_global_load_lds(GLB(Bhi_ + gb), LDS(&Bs_h[rseg][0]), 16, 0, 0); \
            __builtin_amdgcn_global_load_lds(GLB(Blo_ + gb), LDS(&Bs_l[rseg][0]), 16, 0, 0); \
        }                                                                              \
        __syncthreads();                                                               \
        const int kb = (lane >> 4) * 8;                                                \
        short8 ah[4], al[4], bh[4], bl[4];                                             \
        _Pragma("unroll")                                                              \
        for (int mb = 0; mb < 4; ++mb) {                                               \
            const int rr = wr * 64 + mb * 16 + (lane & 15);                            \
            ah[mb] = *(const short8*)&As_h[rr][kb];                                    \
            al[mb] = *(const short8*)&As_l[rr][kb];                                    \
        }                                                                              \
        _Pragma("unroll")                                                              \
        for (int nb = 0; nb < 4; ++nb) {                                               \
            const int cc = wc * 64 + nb * 16 + (lane & 15);                            \
            bh[nb] = *(const short8*)&Bs_h[cc][kb];                                    \
            bl[nb] = *(const short8*)&Bs_l[cc][kb];                                    \
        }                                                                              \
        _Pragma("unroll")                                                              \
        for (int mb = 0; mb < 4; ++mb)                                                 \
            _Pragma("unroll")                                                          \
            for (int nb = 0; nb < 4; ++nb) {                                           \
                acc[mb][nb] = __builtin_amdgcn_mfma_f32_16x16x32_bf16(ah[mb], bh[nb], acc[mb][nb], 0, 0, 0); \
                acc[mb][nb] = __builtin_amdgcn_mfma_f32_16x16x32_bf16(ah[mb], bl[nb], acc[mb][nb], 0, 0, 0); \
                acc[mb][nb] = __builtin_amdgcn_mfma_f32_16x16x32_bf16(al[mb], bh[nb], acc[mb][nb], 0, 0, 0); \
            }                                                                          \
        __syncthreads();                                                               \
    }                                                                                  \
    const int orow = (lane >> 4) * 4;                                                  \
    const int ocol = lane & 15;

// gemm2: fp32 output; B-side (PhiR/xr) k-sparsity -> list from col-tile.
__global__ __launch_bounds__(256) void gemm_mfma_f32out(const short* __restrict__ Ahi,
                                                        const short* __restrict__ Alo,
                                                        const short* __restrict__ Bhi,
                                                        const short* __restrict__ Blo,
                                                        const float* __restrict__ xr,
                                                        float* __restrict__ out) {
    GEMM_BODY(Ahi, Alo, Bhi, Blo, xr, blockIdx.x * 128)
    #pragma unroll
    for (int mb = 0; mb < 4; ++mb)
        #pragma unroll
        for (int nb = 0; nb < 4; ++nb) {
            const int col = col0 + wc * 64 + nb * 16 + ocol;
            #pragma unroll
            for (int reg = 0; reg < 4; ++reg) {
                const int row = row0 + wr * 64 + mb * 16 + orow + reg;
                out[(size_t)row * NN + col] = acc[mb][nb][reg];
            }
        }
}

// gemm1: split-bf16 output; A-side (PhiC/xc) k-sparsity -> list from row-tile.
__global__ __launch_bounds__(256) void gemm_mfma_splitout(const short* __restrict__ Ahi,
                                                          const short* __restrict__ Alo,
                                                          const short* __restrict__ Bhi,
                                                          const short* __restrict__ Blo,
                                                          const float* __restrict__ xc,
                                                          unsigned short* __restrict__ Oh,
                                                          unsigned short* __restrict__ Ol) {
    GEMM_BODY(Ahi, Alo, Bhi, Blo, xc, blockIdx.y * 128)
    #pragma unroll
    for (int mb = 0; mb < 4; ++mb)
        #pragma unroll
        for (int nb = 0; nb < 4; ++nb) {
            const int col = col0 + wc * 64 + nb * 16 + ocol;
            #pragma unroll
            for (int reg = 0; reg < 4; ++reg) {
                const int row = row0 + wr * 64 + mb * 16 + orow + reg;
                unsigned short h, l;
                split_bf16(acc[mb][nb][reg], h, l);
                Oh[(size_t)row * KP + col] = h;
                Ol[(size_t)row * KP + col] = l;
            }
        }
}

extern "C" void kernel_launch(void* const* d_in, const int* in_sizes, int n_in,
                              void* d_out, int out_size, void* d_ws, size_t ws_size,
                              hipStream_t stream) {
    const float* img = (const float*)d_in[0];
    const float* xc  = (const float*)d_in[1];
    const float* xr  = (const float*)d_in[2];
    float* out = (float*)d_out;

    const size_t M2 = (size_t)NN * KP;
    // ws layout (floats): PhiC(2M) | PhiR(2M) | Ubuf(2M) | CdT(256K) | CdTsplit(256K) | idx
    float* PhiC = (float*)d_ws;
    float* PhiR = PhiC + M2;
    float* Ubuf = PhiR + M2;
    float* CdT  = Ubuf + M2;
    float* CdTs = CdT + (size_t)KP * KP;
    int*   idxAll = (int*)(CdTs + (size_t)KP * KP);
    float* Usm  = Ubuf;                             // 501x512 during chain
    unsigned short* PRh = (unsigned short*)Ubuf;    // split(PhiR) -> Ubuf region
    unsigned short* PRl = PRh + M2;
    unsigned short* PCh = (unsigned short*)PhiR;    // split(PhiC) -> PhiR region
    unsigned short* PCl = PCh + M2;
    unsigned short* Ch  = (unsigned short*)CdTs;
    unsigned short* Cl  = Ch + (size_t)KP * KP;
    unsigned short* Uh  = (unsigned short*)PhiC;    // gemm1 out -> PhiC region
    unsigned short* Ul  = Uh + M2;

    // 1: prep (phi tables + nearest + zero CdT)
    fused_pre<<<dim3(2058), 256, 0, stream>>>(xc, xr, PhiC, PhiR, CdT, idxAll);
    // 2: levels 0-2 serial chain in one workgroup
    chain012<<<dim3(1), 1024, 0, stream>>>(img, idxAll, PhiC, PhiR, CdT, Usm);
    // 3-6: heavy phases
    update_wrap<65, 50><<<dim3(128), 256, 0, stream>>>(PhiC, idxAll, CdT, Usm);
    build_wrap<129, 115><<<dim3(66), 256, 0, stream>>>(img, idxAll, Usm, PhiR, CdT);
    update_wrap<129, 115><<<dim3(253), 256, 0, stream>>>(PhiC, idxAll, CdT, Usm);
    build_wrap<257, 244><<<dim3(259), 256, 0, stream>>>(img, idxAll, Usm, PhiR, CdT);
    // 7: split PhiR + CdT (PRh/PRl overlay Usm region - dead now)
    split_two<<<dim3(1152), 256, 0, stream>>>(PhiR, PRh, PRl, CdT, Ch, Cl);
    // 8: split PhiC (overwrites PhiR fp32 region - safe after split_two)
    split_one<<<dim3(1024), 256, 0, stream>>>(PhiC, PCh, PCl);
    // 9: gemm1  U = PhiC x CdT^T  (split-bf16 out into PhiC region)
    gemm_mfma_splitout<<<dim3(KP / 128, NN / 128), 256, 0, stream>>>(
        (const short*)PCh, (const short*)PCl, (const short*)Ch, (const short*)Cl, xc, Uh, Ul);
    // 10: gemm2  out = U x PhiR^T
    gemm_mfma_f32out<<<dim3(NN / 128, NN / 128), 256, 0, stream>>>(
        (const short*)Uh, (const short*)Ul, (const short*)PRh, (const short*)PRl, xr, out);
}

// Round 7
// 228.181 us; speedup vs baseline: 3.6457x; 1.6017x over previous
//
#include <hip/hip_runtime.h>
#include <hip/hip_bf16.h>
#include <cstddef>
#include <cstdint>

#define NN 4096
#define KP 512          // padded K (501 real cols)
#define KTOT 501

typedef __attribute__((ext_vector_type(8))) short short8;
typedef __attribute__((ext_vector_type(4))) float f32x4;

#define GLB(p) ((const __attribute__((address_space(1))) void*)(p))
#define LDS(p) ((__attribute__((address_space(3))) void*)(p))

__device__ __forceinline__ float bf2f(unsigned short u) {
    union { unsigned int i; float f; } v; v.i = ((unsigned int)u) << 16; return v.f;
}

__device__ __forceinline__ void split_bf16(float v, unsigned short& h, unsigned short& l) {
    __hip_bfloat16 hb = __float2bfloat16(v);
    __hip_bfloat16 lb = __float2bfloat16(v - __bfloat162float(hb));
    h = *(unsigned short*)&hb;
    l = *(unsigned short*)&lb;
}

// phi(x) = sin(pi x)/(pi x) * exp(-x^2/(2*3.2^2)), phi(0)=1.
__device__ __forceinline__ float phi_eval(float x) {
    if (x == 0.0f) return 1.0f;
    const float PI_F = 3.14159265358979323846f;
    float rn = rintf(x);
    float r  = x - rn;
    float s  = __sinf(PI_F * r);
    if (((int)rn) & 1) s = -s;
    float e  = __expf(-x * x * (1.0f / 20.48f));
    return __fdividef(s * e, PI_F * x);
}

__device__ __forceinline__ void col_to_level(int col, int& l, int& off) {
    if      (col < 17)  { l = 0; off = 0;   }
    else if (col < 50)  { l = 1; off = 17;  }
    else if (col < 115) { l = 2; off = 50;  }
    else                { l = (col < 244) ? 3 : 4; off = (col < 244) ? 115 : 244; }
}

// ---- kernel 1: fused prep -----------------------------------------------
// blocks [0,1002): nearest; [1002,2026): phi tables (split-bf16 direct);
// [2026,2058): zero Ch/Cl (contiguous 1 MB).
__global__ __launch_bounds__(256) void fused_pre(const float* __restrict__ xc,
                                                 const float* __restrict__ xr,
                                                 unsigned short* __restrict__ PCh,
                                                 unsigned short* __restrict__ PCl,
                                                 unsigned short* __restrict__ PRh,
                                                 unsigned short* __restrict__ PRl,
                                                 unsigned short* __restrict__ Ch,
                                                 int* __restrict__ idxAll) {
    __shared__ float sv[256];
    __shared__ int   si[256];
    const int b = blockIdx.x;
    const int tid = threadIdx.x;
    if (b < 2 * KTOT) {
        int side = (b >= KTOT);
        int col  = side ? b - KTOT : b;
        const float* x = side ? xr : xc;
        int l, off; col_to_level(col, l, off);
        int s = 8 << l;
        float target = (float)(col - off - s) / (float)s;
        float best = 1e30f; int bidx = 0;
        for (int n = tid; n < NN; n += 256) {
            float d = fabsf(x[n] - target);
            if (d < best) { best = d; bidx = n; }
        }
        sv[tid] = best; si[tid] = bidx;
        __syncthreads();
        for (int w = 128; w > 0; w >>= 1) {
            if (tid < w) {
                float ov = sv[tid + w]; int oi = si[tid + w];
                if (ov < sv[tid] || (ov == sv[tid] && oi < si[tid])) { sv[tid] = ov; si[tid] = oi; }
            }
            __syncthreads();
        }
        if (tid == 0) idxAll[b] = si[0];
    } else if (b < 2026) {
        const int i0 = (b - 1002) * 2048 + tid;
        #pragma unroll
        for (int j = 0; j < 8; ++j) {
            int i = i0 + j * 256;
            int n = i >> 9, col = i & 511;
            float pc = 0.f, pr = 0.f;
            if (col < KTOT) {
                int l, off; col_to_level(col, l, off);
                int s = 8 << l;
                float fo = (float)(col - off - s);
                float fs = (float)s;
                pc = phi_eval(fs * xc[n] - fo);
                pr = phi_eval(fs * xr[n] - fo);
            }
            unsigned short h, l2;
            split_bf16(pc, h, l2); PCh[i] = h; PCl[i] = l2;
            split_bf16(pr, h, l2); PRh[i] = h; PRl[i] = l2;
        }
    } else {
        // zero Ch+Cl: contiguous 2*KP*KP ushorts = 64K uint4
        uint4* z = (uint4*)Ch;
        const int g0 = (b - 2026) * 256 + tid;
        #pragma unroll
        for (int j = 0; j < 8; ++j) {
            int g = g0 + j * 8192;
            z[g] = make_uint4(0u, 0u, 0u, 0u);
        }
    }
}

// ---- chain: build_k / update_k (per-phase launches) ---------------------

template<int T, int OFF>
__global__ __launch_bounds__(256) void build_k(const float* __restrict__ img,
                                               const int* __restrict__ idxAll,
                                               const float* __restrict__ Usm,
                                               const unsigned short* __restrict__ PRh,
                                               const unsigned short* __restrict__ PRl,
                                               float* __restrict__ CdT,
                                               unsigned short* __restrict__ Ch,
                                               unsigned short* __restrict__ Cl) {
    int i = blockIdx.x * 256 + threadIdx.x;
    if (i >= T * T) return;
    int p = i / T, q = i - p * T;
    int ip = idxAll[OFF + p];
    int iq = idxAll[KTOT + OFF + q];
    float f = img[(size_t)ip * NN + iq];
    float val;
    if (OFF == 0) {
        val = f;
    } else {
        const float* u = Usm + (size_t)(OFF + p) * KP;       // 16B aligned, k from 0
        const unsigned short* ph = PRh + (size_t)iq * KP;
        const unsigned short* pl = PRl + (size_t)iq * KP;
        float s0 = 0.f, s1 = 0.f, s2 = 0.f, s3 = 0.f;
        int k = 0;
        #pragma unroll 4
        for (; k + 4 <= OFF; k += 4) {
            ushort4 h4 = *(const ushort4*)(ph + k);
            ushort4 l4 = *(const ushort4*)(pl + k);
            float4  b4 = *(const float4*)(u + k);
            s0 += (bf2f(h4.x) + bf2f(l4.x)) * b4.x;
            s1 += (bf2f(h4.y) + bf2f(l4.y)) * b4.y;
            s2 += (bf2f(h4.z) + bf2f(l4.z)) * b4.z;
            s3 += (bf2f(h4.w) + bf2f(l4.w)) * b4.w;
        }
        float uu = (s0 + s1) + (s2 + s3);
        for (; k < OFF; ++k) uu += (bf2f(ph[k]) + bf2f(pl[k])) * u[k];
        float d = f - uu;
        val = (fabsf(d) > 0.01f) ? d : 0.0f;
    }
    size_t o = (size_t)(OFF + q) * KP + (OFF + p);           // dense transposed
    CdT[o] = val;
    unsigned short h, l;
    split_bf16(val, h, l);
    Ch[o] = h; Cl[o] = l;
}

template<int T, int OFF>
__global__ __launch_bounds__(256) void update_k(const unsigned short* __restrict__ PCh,
                                                const unsigned short* __restrict__ PCl,
                                                const int* __restrict__ idxAll,
                                                const float* __restrict__ CdT,
                                                float* __restrict__ Usm) {
    int i = blockIdx.x * 256 + threadIdx.x;
    if (i >= KTOT * T) return;
    int r = i / T, t = i - r * T;
    const unsigned short* ah = PCh + (size_t)idxAll[r] * KP + OFF;
    const unsigned short* al = PCl + (size_t)idxAll[r] * KP + OFF;
    const float* b = CdT + (size_t)(OFF + t) * KP + OFF;
    constexpr int HEAD = (4 - (OFF & 3)) & 3;
    float s = 0.f;
    int k = 0;
    #pragma unroll
    for (; k < HEAD; ++k) s += (bf2f(ah[k]) + bf2f(al[k])) * b[k];
    float s0 = 0.f, s1 = 0.f, s2 = 0.f, s3 = 0.f;
    #pragma unroll 4
    for (; k + 4 <= T; k += 4) {
        ushort4 h4 = *(const ushort4*)(ah + k);
        ushort4 l4 = *(const ushort4*)(al + k);
        float4  b4 = *(const float4*)(b + k);
        s0 += (bf2f(h4.x) + bf2f(l4.x)) * b4.x;
        s1 += (bf2f(h4.y) + bf2f(l4.y)) * b4.y;
        s2 += (bf2f(h4.z) + bf2f(l4.z)) * b4.z;
        s3 += (bf2f(h4.w) + bf2f(l4.w)) * b4.w;
    }
    s += (s0 + s1) + (s2 + s3);
    for (; k < T; ++k) s += (bf2f(ah[k]) + bf2f(al[k])) * b[k];
    Usm[(size_t)r * KP + OFF + t] = s;
}

// ---- MFMA GEMMs with per-tile k-chunk skipping --------------------------
// A-side mask from sorted x (|s*x - k| <= 12.5 support); BMASK_ is a static
// extra mask (gemm1: C block-diagonal structure; gemm2: all-ones).
#define GEMM_BODY(Ahi_, Alo_, Bhi_, Blo_, XARR_, XBASE_, BMASK_)                       \
    __shared__ short As_h[128][32];                                                    \
    __shared__ short As_l[128][32];                                                    \
    __shared__ short Bs_h[128][32];                                                    \
    __shared__ short Bs_l[128][32];                                                    \
    const int tid  = threadIdx.x;                                                      \
    const int lane = tid & 63;                                                         \
    const int wave = tid >> 6;                                                         \
    const int wr   = wave >> 1;                                                        \
    const int wc   = wave & 1;                                                         \
    const int row0 = blockIdx.y * 128;                                                 \
    const int col0 = blockIdx.x * 128;                                                 \
    int list[16]; int nch = 0;                                                         \
    {                                                                                  \
        float xmn = XARR_[XBASE_];                                                     \
        float xmx = XARR_[(XBASE_) + 127];                                             \
        int mask = 0;                                                                  \
        const int off_[5] = {0, 17, 50, 115, 244};                                     \
        _Pragma("unroll")                                                              \
        for (int l = 0; l < 5; ++l) {                                                  \
            int s_ = 8 << l;                                                           \
            int clo = off_[l] + s_ + (int)floorf(s_ * xmn - 12.5f);                    \
            int chi = off_[l] + s_ + (int)ceilf (s_ * xmx + 12.5f);                    \
            if (clo < off_[l]) clo = off_[l];                                          \
            if (chi > off_[l] + 2 * s_) chi = off_[l] + 2 * s_;                        \
            for (int c = clo >> 5; c <= (chi >> 5); ++c) mask |= 1 << c;               \
        }                                                                              \
        mask &= (BMASK_);                                                              \
        for (int c = 0; c < 16; ++c) if ((mask >> c) & 1) list[nch++] = c;             \
    }                                                                                  \
    f32x4 acc[4][4];                                                                   \
    _Pragma("unroll")                                                                  \
    for (int i = 0; i < 4; ++i)                                                        \
        _Pragma("unroll")                                                              \
        for (int j = 0; j < 4; ++j) acc[i][j] = (f32x4){0.f, 0.f, 0.f, 0.f};           \
    const int srow = lane >> 2;                                                        \
    const int scol = (lane & 3) * 8;                                                   \
    for (int ic = 0; ic < nch; ++ic) {                                                 \
        const int k0 = list[ic] * 32;                                                  \
        _Pragma("unroll")                                                              \
        for (int s = 0; s < 2; ++s) {                                                  \
            const int rseg = wave * 32 + s * 16;                                       \
            const int r    = rseg + srow;                                              \
            const size_t ga = (size_t)(row0 + r) * KP + k0 + scol;                     \
            const size_t gb = (size_t)(col0 + r) * KP + k0 + scol;                     \
            __builtin_amdgcn_global_load_lds(GLB(Ahi_ + ga), LDS(&As_h[rseg][0]), 16, 0, 0); \
            __builtin_amdgcn_global_load_lds(GLB(Alo_ + ga), LDS(&As_l[rseg][0]), 16, 0, 0); \
            __builtin_amdgcn_global_load_lds(GLB(Bhi_ + gb), LDS(&Bs_h[rseg][0]), 16, 0, 0); \
            __builtin_amdgcn_global_load_lds(GLB(Blo_ + gb), LDS(&Bs_l[rseg][0]), 16, 0, 0); \
        }                                                                              \
        __syncthreads();                                                               \
        const int kb = (lane >> 4) * 8;                                                \
        short8 ah[4], al[4], bh[4], bl[4];                                             \
        _Pragma("unroll")                                                              \
        for (int mb = 0; mb < 4; ++mb) {                                               \
            const int rr = wr * 64 + mb * 16 + (lane & 15);                            \
            ah[mb] = *(const short8*)&As_h[rr][kb];                                    \
            al[mb] = *(const short8*)&As_l[rr][kb];                                    \
        }                                                                              \
        _Pragma("unroll")                                                              \
        for (int nb = 0; nb < 4; ++nb) {                                               \
            const int cc = wc * 64 + nb * 16 + (lane & 15);                            \
            bh[nb] = *(const short8*)&Bs_h[cc][kb];                                    \
            bl[nb] = *(const short8*)&Bs_l[cc][kb];                                    \
        }                                                                              \
        _Pragma("unroll")                                                              \
        for (int mb = 0; mb < 4; ++mb)                                                 \
            _Pragma("unroll")                                                          \
            for (int nb = 0; nb < 4; ++nb) {                                           \
                acc[mb][nb] = __builtin_amdgcn_mfma_f32_16x16x32_bf16(ah[mb], bh[nb], acc[mb][nb], 0, 0, 0); \
                acc[mb][nb] = __builtin_amdgcn_mfma_f32_16x16x32_bf16(ah[mb], bl[nb], acc[mb][nb], 0, 0, 0); \
                acc[mb][nb] = __builtin_amdgcn_mfma_f32_16x16x32_bf16(al[mb], bh[nb], acc[mb][nb], 0, 0, 0); \
            }                                                                          \
        __syncthreads();                                                               \
    }                                                                                  \
    const int orow = (lane >> 4) * 4;                                                  \
    const int ocol = lane & 15;

// gemm2: out = U x PhiR^T, fp32 out; B-side (xr) k-sparsity from col-tile.
__global__ __launch_bounds__(256) void gemm_mfma_f32out(const short* __restrict__ Ahi,
                                                        const short* __restrict__ Alo,
                                                        const short* __restrict__ Bhi,
                                                        const short* __restrict__ Blo,
                                                        const float* __restrict__ xr,
                                                        float* __restrict__ out) {
    GEMM_BODY(Ahi, Alo, Bhi, Blo, xr, blockIdx.x * 128, 0xFFFF)
    #pragma unroll
    for (int mb = 0; mb < 4; ++mb)
        #pragma unroll
        for (int nb = 0; nb < 4; ++nb) {
            const int col = col0 + wc * 64 + nb * 16 + ocol;
            #pragma unroll
            for (int reg = 0; reg < 4; ++reg) {
                const int row = row0 + wr * 64 + mb * 16 + orow + reg;
                out[(size_t)row * NN + col] = acc[mb][nb][reg];
            }
        }
}

// gemm1: U = PhiC x C^T, split-bf16 out; A-side (xc) sparsity AND static
// block-diagonal B mask by col-tile.
__global__ __launch_bounds__(256) void gemm_mfma_splitout(const short* __restrict__ Ahi,
                                                          const short* __restrict__ Alo,
                                                          const short* __restrict__ Bhi,
                                                          const short* __restrict__ Blo,
                                                          const float* __restrict__ xc,
                                                          unsigned short* __restrict__ Oh,
                                                          unsigned short* __restrict__ Ol) {
    const int bmask_tab[4] = {0x00FF, 0xFFF8, 0xFF80, 0xFF80};
    const int bm = bmask_tab[blockIdx.x];
    GEMM_BODY(Ahi, Alo, Bhi, Blo, xc, blockIdx.y * 128, bm)
    #pragma unroll
    for (int mb = 0; mb < 4; ++mb)
        #pragma unroll
        for (int nb = 0; nb < 4; ++nb) {
            const int col = col0 + wc * 64 + nb * 16 + ocol;
            #pragma unroll
            for (int reg = 0; reg < 4; ++reg) {
                const int row = row0 + wr * 64 + mb * 16 + orow + reg;
                unsigned short h, l;
                split_bf16(acc[mb][nb][reg], h, l);
                Oh[(size_t)row * KP + col] = h;
                Ol[(size_t)row * KP + col] = l;
            }
        }
}

extern "C" void kernel_launch(void* const* d_in, const int* in_sizes, int n_in,
                              void* d_out, int out_size, void* d_ws, size_t ws_size,
                              hipStream_t stream) {
    const float* img = (const float*)d_in[0];
    const float* xc  = (const float*)d_in[1];
    const float* xr  = (const float*)d_in[2];
    float* out = (float*)d_out;

    const size_t M2 = (size_t)NN * KP;
    // ws: PCh|PCl|PRh|PRl|Uh|Ul (6 x 4MB bf16) | Usm(1MB) | CdT(1MB) | Ch|Cl(1MB) | idx
    unsigned short* PCh = (unsigned short*)d_ws;
    unsigned short* PCl = PCh + M2;
    unsigned short* PRh = PCl + M2;
    unsigned short* PRl = PRh + M2;
    unsigned short* Uh  = PRl + M2;
    unsigned short* Ul  = Uh + M2;
    float* Usm = (float*)(Ul + M2);
    float* CdT = Usm + (size_t)KP * KP;
    unsigned short* Ch = (unsigned short*)(CdT + (size_t)KP * KP);
    unsigned short* Cl = Ch + (size_t)KP * KP;
    int* idxAll = (int*)(Cl + (size_t)KP * KP);

    // 1: prep (nearest + split phi tables + zero Ch/Cl)
    fused_pre<<<dim3(2058), 256, 0, stream>>>(xc, xr, PCh, PCl, PRh, PRl, Ch, idxAll);
    // 2-10: serial level chain, each phase multi-block
    build_k<17, 0>   <<<dim3(2),   256, 0, stream>>>(img, idxAll, Usm, PRh, PRl, CdT, Ch, Cl);
    update_k<17, 0>  <<<dim3(34),  256, 0, stream>>>(PCh, PCl, idxAll, CdT, Usm);
    build_k<33, 17>  <<<dim3(5),   256, 0, stream>>>(img, idxAll, Usm, PRh, PRl, CdT, Ch, Cl);
    update_k<33, 17> <<<dim3(65),  256, 0, stream>>>(PCh, PCl, idxAll, CdT, Usm);
    build_k<65, 50>  <<<dim3(17),  256, 0, stream>>>(img, idxAll, Usm, PRh, PRl, CdT, Ch, Cl);
    update_k<65, 50> <<<dim3(128), 256, 0, stream>>>(PCh, PCl, idxAll, CdT, Usm);
    build_k<129, 115><<<dim3(66),  256, 0, stream>>>(img, idxAll, Usm, PRh, PRl, CdT, Ch, Cl);
    update_k<129, 115><<<dim3(253), 256, 0, stream>>>(PCh, PCl, idxAll, CdT, Usm);
    build_k<257, 244><<<dim3(259), 256, 0, stream>>>(img, idxAll, Usm, PRh, PRl, CdT, Ch, Cl);
    // 11: gemm1  U = PhiC x C^T (split-bf16 out)
    gemm_mfma_splitout<<<dim3(KP / 128, NN / 128), 256, 0, stream>>>(
        (const short*)PCh, (const short*)PCl, (const short*)Ch, (const short*)Cl, xc, Uh, Ul);
    // 12: gemm2  out = U x PhiR^T
    gemm_mfma_f32out<<<dim3(NN / 128, NN / 128), 256, 0, stream>>>(
        (const short*)Uh, (const short*)Ul, (const short*)PRh, (const short*)PRl, xr, out);
}